// Round 1
// baseline (1796.603 us; speedup 1.0000x reference)
//
#include <hip/hip_runtime.h>
#include <math.h>

// Problem constants
#define BB 4
#define CC 256
#define HH 64
#define WW 64
#define KP 9
#define GG 32
#define HWW (HH*WW)          // 4096
#define FEL ((size_t)BB*CC*HH*WW)  // 4194304
#define GN_CNT 32768.0f      // (CC/GG)*H*W = 8*4096

// ---------------------------------------------------------------------------
// zero GN stats (3 tensors x 4 b x 32 g x 2)
__global__ void zero_stats(float* s) {
    int i = blockIdx.x * 256 + threadIdx.x;
    if (i < 768) s[i] = 0.f;
}

// ---------------------------------------------------------------------------
// NCHW -> NHWC transpose for both feature maps.
// grid (4 c-tiles, 64 y, 8: z&3=b, z>>2=which), block 256
__global__ void transpose_nchw_nhwc(const float* __restrict__ cls,
                                    const float* __restrict__ reg,
                                    float* __restrict__ out_cls,
                                    float* __restrict__ out_reg) {
    __shared__ float tile[64][65];
    int c0 = blockIdx.x * 64;
    int y  = blockIdx.y;
    int b  = blockIdx.z & 3;
    const float* in = (blockIdx.z >> 2) ? reg : cls;
    float* out      = (blockIdx.z >> 2) ? out_reg : out_cls;
    int lx = threadIdx.x & 63;
    int q  = threadIdx.x >> 6;
    for (int j = 0; j < 16; ++j) {
        int ci = q * 16 + j;
        tile[ci][lx] = in[(((size_t)b*CC + c0 + ci)*HH + y)*WW + lx];
    }
    __syncthreads();
    for (int j = 0; j < 16; ++j) {
        int xi = q * 16 + j;
        out[(((size_t)b*HH + y)*WW + xi)*CC + c0 + lx] = tile[lx][xi];
    }
}

// ---------------------------------------------------------------------------
// weight transpose: in [Co][256][3][3] (or [Co][256][1][9]) -> out [9][Co][256]
__global__ void transpose_w3(const float* __restrict__ w, float* __restrict__ wt, int Co) {
    int idx = blockIdx.x * 256 + threadIdx.x;
    int total = 9 * Co * 256;
    if (idx >= total) return;
    int c  = idx & 255;
    int o  = (idx >> 8) % Co;
    int kk = idx / (256 * Co);
    wt[idx] = w[(o * 256 + c) * 9 + kk];
}

// ---------------------------------------------------------------------------
// conv3x3, Cin=256, Cout=256, channels-last in/out, + bias + GN stats.
// grid (2 x-halves, 64 y, 4 b), block 256 (thread = out channel o)
__global__ __launch_bounds__(256, 2) void conv3x3_c256(
    const float* __restrict__ in_cl,   // [B,H,W,256]
    const float* __restrict__ wt,      // [9][256 o][256 c]
    const float* __restrict__ bias,    // [256]
    float* __restrict__ out_cl,        // [B,H,W,256]
    float* __restrict__ stats)         // [4][32][2]
{
    __shared__ float v[34 * 256];
    int x0 = blockIdx.x * 32;
    int y  = blockIdx.y;
    int b  = blockIdx.z;
    int o  = threadIdx.x;
    float acc[32];
    float bi = bias[o];
    #pragma unroll
    for (int i = 0; i < 32; ++i) acc[i] = bi;

    for (int ky = 0; ky < 3; ++ky) {
        int yy = y + ky - 1;
        bool yok = (yy >= 0 && yy < HH);
        const float* src = in_cl + ((size_t)(b*HH + (yok ? yy : 0)) * WW) * CC;
        __syncthreads();
        for (int xx = 0; xx < 34; ++xx) {
            int gx = x0 - 1 + xx;
            float val = 0.f;
            if (yok && gx >= 0 && gx < WW) val = src[(size_t)gx * CC + o];
            v[xx * 256 + o] = val;
        }
        __syncthreads();
        for (int kx = 0; kx < 3; ++kx) {
            const float* wrow = wt + ((size_t)((ky*3 + kx) * 256 + o)) * 256;
            for (int c4 = 0; c4 < 64; ++c4) {
                float4 wq = *(const float4*)(wrow + c4 * 4);
                #pragma unroll
                for (int x = 0; x < 32; ++x) {
                    float4 vq = *(const float4*)(&v[(x + kx) * 256 + c4 * 4]);
                    acc[x] += wq.x*vq.x + wq.y*vq.y + wq.z*vq.z + wq.w*vq.w;
                }
            }
        }
    }
    // write out + GN partial stats
    float s1 = 0.f, s2 = 0.f;
    for (int x = 0; x < 32; ++x) {
        float t = acc[x];
        s1 += t; s2 += t * t;
        out_cl[(((size_t)b*HH + y)*WW + x0 + x)*CC + o] = t;
    }
    __syncthreads();
    v[o] = s1; v[256 + o] = s2;
    __syncthreads();
    if (o < 32) {
        float a1 = 0.f, a2 = 0.f;
        for (int j = 0; j < 8; ++j) { a1 += v[o*8 + j]; a2 += v[256 + o*8 + j]; }
        atomicAdd(&stats[(b*32 + o)*2],     a1);
        atomicAdd(&stats[(b*32 + o)*2 + 1], a2);
    }
}

// ---------------------------------------------------------------------------
// GN + ReLU on channels-last tensor, in place. grid 4096 x 256 threads (float4)
__global__ void gn_relu_cl(float* __restrict__ t, const float* __restrict__ stats,
                           const float* __restrict__ gamma, const float* __restrict__ beta) {
    size_t e = ((size_t)blockIdx.x * 256 + threadIdx.x) * 4;
    int c = (int)(e & 255);
    int b = (int)(e >> 20);
    int g = c >> 3;
    float mu = stats[(b*32 + g)*2] * (1.f / GN_CNT);
    float ms = stats[(b*32 + g)*2 + 1] * (1.f / GN_CNT);
    float rs = rsqrtf(ms - mu*mu + 1e-5f);
    float4 vv = *(const float4*)(t + e);
    float4 r;
    r.x = fmaxf((vv.x - mu)*rs*gamma[c]   + beta[c],   0.f);
    r.y = fmaxf((vv.y - mu)*rs*gamma[c+1] + beta[c+1], 0.f);
    r.z = fmaxf((vv.z - mu)*rs*gamma[c+2] + beta[c+2], 0.f);
    r.w = fmaxf((vv.w - mu)*rs*gamma[c+3] + beta[c+3], 0.f);
    *(float4*)(t + e) = r;
}

// ---------------------------------------------------------------------------
// conv3x3, Cin=256, Cout=18 (offset head). Writes pts (NCHW, fp32, into d_out).
// grid (64 y, 4 b), block 256: lane x = tid&63, oq = tid>>6; o = oq + 4j.
__global__ __launch_bounds__(256, 2) void conv3x3_c18(
    const float* __restrict__ in_cl,   // [B,H,W,256]
    const float* __restrict__ wt,      // [9][18][256]
    const float* __restrict__ bias,    // [18]
    float* __restrict__ pts)           // [B,18,H,W]
{
    __shared__ float v[66 * 132];
    int y = blockIdx.x;
    int b = blockIdx.y;
    int x  = threadIdx.x & 63;
    int oq = threadIdx.x >> 6;
    int no = (oq < 2) ? 5 : 4;
    float acc[5] = {0.f, 0.f, 0.f, 0.f, 0.f};

    for (int ky = 0; ky < 3; ++ky) {
        int yy = y + ky - 1;
        bool yok = (yy >= 0 && yy < HH);
        const float* src = in_cl + ((size_t)(b*HH + (yok ? yy : 0)) * WW) * CC;
        for (int ch = 0; ch < 2; ++ch) {
            __syncthreads();
            int cs = threadIdx.x & 127;
            int xp = threadIdx.x >> 7;
            for (int xx = xp; xx < 66; xx += 2) {
                int gx = xx - 1;
                float val = 0.f;
                if (yok && gx >= 0 && gx < WW) val = src[(size_t)gx*CC + ch*128 + cs];
                v[xx * 132 + cs] = val;
            }
            __syncthreads();
            for (int kx = 0; kx < 3; ++kx) {
                int xi = x + kx;
                for (int c4 = 0; c4 < 32; ++c4) {
                    float4 vq = *(const float4*)(&v[xi * 132 + c4 * 4]);
                    #pragma unroll
                    for (int j = 0; j < 5; ++j) {
                        if (j < no) {
                            int o = oq + 4 * j;
                            float4 wq = *(const float4*)(&wt[((size_t)((ky*3+kx)*18 + o))*256 + ch*128 + c4*4]);
                            acc[j] += wq.x*vq.x + wq.y*vq.y + wq.z*vq.z + wq.w*vq.w;
                        }
                    }
                }
            }
        }
    }
    for (int j = 0; j < no; ++j) {
        int o = oq + 4 * j;
        pts[(((size_t)b*18 + o)*HH + y)*WW + x] = acc[j] + bias[o];
    }
}

// ---------------------------------------------------------------------------
// Deformable conv (both cls and reg paths). Sampling at (y+pts_y, x+pts_x):
// the base-offset grid cancels exactly against the sampler's base grid.
// grid (2 x-halves, 64 y, 8: z&3=b, z>>2=which), block 256 (thread = o)
__global__ __launch_bounds__(256, 2) void deform_conv_k(
    const float* __restrict__ cls_cl, const float* __restrict__ reg_cl, // [B,H,W,256]
    const float* __restrict__ wtc, const float* __restrict__ wtr,       // [9][256][256]
    const float* __restrict__ pts,                                      // [B,18,H,W]
    float* __restrict__ out_cls, float* __restrict__ out_reg,           // [B,256,H,W]
    float* __restrict__ stats_cls, float* __restrict__ stats_reg)
{
    __shared__ float v[32 * 256];
    int x0 = blockIdx.x * 32;
    int y  = blockIdx.y;
    int b  = blockIdx.z & 3;
    int which = blockIdx.z >> 2;
    const float* feat = which ? reg_cl : cls_cl;
    const float* wt   = which ? wtr : wtc;
    float* outp  = which ? out_reg : out_cls;
    float* stats = which ? stats_reg : stats_cls;
    int o = threadIdx.x;
    const float* featb = feat + (size_t)b * HWW * CC;

    float acc[32];
    #pragma unroll
    for (int i = 0; i < 32; ++i) acc[i] = 0.f;

    for (int k = 0; k < KP; ++k) {
        const float* py_row = pts + (((size_t)b*18 + 2*k)*HH + y)*WW + x0;
        const float* px_row = py_row + HWW;   // channel 2k+1
        __syncthreads();
        for (int x = 0; x < 32; ++x) {
            float py = py_row[x] + (float)y;
            float px = px_row[x] + (float)(x0 + x);
            float y0f = floorf(py), x0f = floorf(px);
            float wy = py - y0f, wx = px - x0f;
            int iy0 = (int)y0f, ix0 = (int)x0f;
            int iy1 = iy0 + 1,  ix1 = ix0 + 1;
            bool vy0 = (iy0 >= 0 && iy0 < HH), vy1 = (iy1 >= 0 && iy1 < HH);
            bool vx0 = (ix0 >= 0 && ix0 < WW), vx1 = (ix1 >= 0 && ix1 < WW);
            int cy0 = min(max(iy0, 0), HH-1), cy1 = min(max(iy1, 0), HH-1);
            int cx0 = min(max(ix0, 0), WW-1), cx1 = min(max(ix1, 0), WW-1);
            float w00 = (1.f-wy)*(1.f-wx) * ((vy0 && vx0) ? 1.f : 0.f);
            float w01 = (1.f-wy)*wx       * ((vy0 && vx1) ? 1.f : 0.f);
            float w10 = wy*(1.f-wx)       * ((vy1 && vx0) ? 1.f : 0.f);
            float w11 = wy*wx             * ((vy1 && vx1) ? 1.f : 0.f);
            const float* p00 = featb + ((size_t)cy0*WW + cx0)*CC + o;
            const float* p01 = featb + ((size_t)cy0*WW + cx1)*CC + o;
            const float* p10 = featb + ((size_t)cy1*WW + cx0)*CC + o;
            const float* p11 = featb + ((size_t)cy1*WW + cx1)*CC + o;
            v[x * 256 + o] = w00*p00[0] + w01*p01[0] + w10*p10[0] + w11*p11[0];
        }
        __syncthreads();
        const float* wrow = wt + ((size_t)k*256 + o) * 256;
        for (int c4 = 0; c4 < 64; ++c4) {
            float4 wq = *(const float4*)(wrow + c4 * 4);
            #pragma unroll
            for (int x = 0; x < 32; ++x) {
                float4 vq = *(const float4*)(&v[x * 256 + c4 * 4]);
                acc[x] += wq.x*vq.x + wq.y*vq.y + wq.z*vq.z + wq.w*vq.w;
            }
        }
    }
    // write NCHW + GN stats
    float s1 = 0.f, s2 = 0.f;
    float* orow = outp + (((size_t)b*CC + o)*HH + y)*WW + x0;
    #pragma unroll
    for (int x = 0; x < 32; ++x) {
        float t = acc[x];
        s1 += t; s2 += t * t;
        orow[x] = t;
    }
    __syncthreads();
    v[o] = s1; v[256 + o] = s2;
    __syncthreads();
    if (o < 32) {
        float a1 = 0.f, a2 = 0.f;
        for (int j = 0; j < 8; ++j) { a1 += v[o*8 + j]; a2 += v[256 + o*8 + j]; }
        atomicAdd(&stats[(b*32 + o)*2],     a1);
        atomicAdd(&stats[(b*32 + o)*2 + 1], a2);
    }
}

// ---------------------------------------------------------------------------
// GN + ReLU on NCHW deform outputs -> final outputs. grid (4096, 2)
__global__ void gn_relu_nchw(const float* __restrict__ in_cls, const float* __restrict__ in_reg,
                             float* __restrict__ out_cls, float* __restrict__ out_reg,
                             const float* __restrict__ stats_base,
                             const float* __restrict__ gcls, const float* __restrict__ bcls,
                             const float* __restrict__ greg, const float* __restrict__ breg) {
    int which = blockIdx.y;
    const float* in  = which ? in_reg  : in_cls;
    float* out       = which ? out_reg : out_cls;
    const float* st  = stats_base + (which ? 512 : 256);
    const float* gg  = which ? greg : gcls;
    const float* be  = which ? breg : bcls;
    size_t e = ((size_t)blockIdx.x * 256 + threadIdx.x) * 4;
    int c = (int)((e >> 12) & 255);
    int b = (int)(e >> 20);
    int g = c >> 3;
    float mu = st[(b*32 + g)*2] * (1.f / GN_CNT);
    float ms = st[(b*32 + g)*2 + 1] * (1.f / GN_CNT);
    float rs = rsqrtf(ms - mu*mu + 1e-5f);
    float ga = gg[c], bb = be[c];
    float4 vv = *(const float4*)(in + e);
    float4 r;
    r.x = fmaxf((vv.x - mu)*rs*ga + bb, 0.f);
    r.y = fmaxf((vv.y - mu)*rs*ga + bb, 0.f);
    r.z = fmaxf((vv.z - mu)*rs*ga + bb, 0.f);
    r.w = fmaxf((vv.w - mu)*rs*ga + bb, 0.f);
    *(float4*)(out + e) = r;
}

// ---------------------------------------------------------------------------
extern "C" void kernel_launch(void* const* d_in, const int* in_sizes, int n_in,
                              void* d_out, int out_size, void* d_ws, size_t ws_size,
                              hipStream_t stream) {
    (void)in_sizes; (void)n_in; (void)out_size; (void)ws_size;
    const float* cls_feat = (const float*)d_in[0];
    const float* reg_feat = (const float*)d_in[1];
    const float* offc_w   = (const float*)d_in[2];
    const float* offc_b   = (const float*)d_in[3];
    const float* offc_g   = (const float*)d_in[4];
    const float* offc_bt  = (const float*)d_in[5];
    const float* offo_w   = (const float*)d_in[6];
    const float* offo_b   = (const float*)d_in[7];
    const float* clsdc_w  = (const float*)d_in[8];
    const float* cls_g    = (const float*)d_in[9];
    const float* cls_bt   = (const float*)d_in[10];
    const float* regdc_w  = (const float*)d_in[11];
    const float* reg_g    = (const float*)d_in[12];
    const float* reg_bt   = (const float*)d_in[13];
    float* out = (float*)d_out;

    float* ws = (float*)d_ws;
    const size_t F = FEL;              // 4194304 floats
    float* reg_cl = ws;
    float* cls_cl = ws + F;
    float* t_cl   = ws + 2*F;          // conv1 out / post-GN t; later reused as dc_cls
    float* dc_reg = ws + 3*F;
    float* wt1 = ws + 4*F;             // [9][256][256]  589824
    float* wt2 = wt1 + 589824;         // [9][18][256]   41472
    float* wtc = wt2 + 41472;          // 589824
    float* wtr = wtc + 589824;         // 589824
    float* stats = wtr + 589824;       // 768 floats: conv1 | cls | reg

    float* pts     = out;              // [4,18,64,64]
    float* out_cls = out + 294912;
    float* out_reg = out + 294912 + F;
    float* dc_cls  = t_cl;             // safe alias: t consumed before deform runs

    hipLaunchKernelGGL(zero_stats, dim3(3), dim3(256), 0, stream, stats);
    hipLaunchKernelGGL(transpose_nchw_nhwc, dim3(4, 64, 8), dim3(256), 0, stream,
                       cls_feat, reg_feat, cls_cl, reg_cl);
    hipLaunchKernelGGL(transpose_w3, dim3(2304), dim3(256), 0, stream, offc_w, wt1, 256);
    hipLaunchKernelGGL(transpose_w3, dim3(162),  dim3(256), 0, stream, offo_w, wt2, 18);
    hipLaunchKernelGGL(transpose_w3, dim3(2304), dim3(256), 0, stream, clsdc_w, wtc, 256);
    hipLaunchKernelGGL(transpose_w3, dim3(2304), dim3(256), 0, stream, regdc_w, wtr, 256);
    hipLaunchKernelGGL(conv3x3_c256, dim3(2, 64, 4), dim3(256), 0, stream,
                       reg_cl, wt1, offc_b, t_cl, stats);
    hipLaunchKernelGGL(gn_relu_cl, dim3(4096), dim3(256), 0, stream,
                       t_cl, stats, offc_g, offc_bt);
    hipLaunchKernelGGL(conv3x3_c18, dim3(64, 4), dim3(256), 0, stream,
                       t_cl, wt2, offo_b, pts);
    hipLaunchKernelGGL(deform_conv_k, dim3(2, 64, 8), dim3(256), 0, stream,
                       cls_cl, reg_cl, wtc, wtr, pts, dc_cls, dc_reg,
                       stats + 256, stats + 512);
    hipLaunchKernelGGL(gn_relu_nchw, dim3(4096, 2), dim3(256), 0, stream,
                       dc_cls, dc_reg, out_cls, out_reg,
                       stats, cls_g, cls_bt, reg_g, reg_bt);
}

// Round 2
// 504.772 us; speedup vs baseline: 3.5592x; 3.5592x over previous
//
#include <hip/hip_runtime.h>
#include <math.h>

#define BB 4
#define CC 256
#define HH 64
#define WW 64
#define KP 9
#define GG 32
#define HWW (HH*WW)                 // 4096
#define FEL ((size_t)BB*CC*HH*WW)   // 4194304
#define GN_CNT 32768.0f             // (CC/GG)*H*W

typedef __bf16 bf16x8 __attribute__((ext_vector_type(8)));
typedef float  f32x4  __attribute__((ext_vector_type(4)));

__device__ __forceinline__ float bflo(unsigned u) {
    union { unsigned u; float f; } x; x.u = u << 16; return x.f;
}
__device__ __forceinline__ float bfhi(unsigned u) {
    union { unsigned u; float f; } x; x.u = u & 0xffff0000u; return x.f;
}

// ---------------------------------------------------------------------------
__global__ void zero_stats(float* s) {
    int i = blockIdx.x * 256 + threadIdx.x;
    if (i < 768) s[i] = 0.f;
}

// ---------------------------------------------------------------------------
// NCHW fp32 -> NHWC bf16 for both feature maps.
__global__ void transpose_feat(const float* __restrict__ cls,
                               const float* __restrict__ reg,
                               __bf16* __restrict__ out_cls,
                               __bf16* __restrict__ out_reg) {
    __shared__ float tile[64][65];
    int c0 = blockIdx.x * 64;
    int y  = blockIdx.y;
    int b  = blockIdx.z & 3;
    const float* in = (blockIdx.z >> 2) ? reg : cls;
    __bf16* out     = (blockIdx.z >> 2) ? out_reg : out_cls;
    int lx = threadIdx.x & 63;
    int q  = threadIdx.x >> 6;
    for (int j = 0; j < 16; ++j) {
        int ci = q * 16 + j;
        tile[ci][lx] = in[(((size_t)b*CC + c0 + ci)*HH + y)*WW + lx];
    }
    __syncthreads();
    for (int j = 0; j < 16; ++j) {
        int xi = q * 16 + j;
        out[(((size_t)b*HH + y)*WW + xi)*CC + c0 + lx] = (__bf16)tile[lx][xi];
    }
}

// ---------------------------------------------------------------------------
// fp32 [O=256][C=256][9] -> bf16 B-fragment order [9][c0:8][o16:16][lane:64][j:8]
// lane l holds W[o16*16 + (l&15)][c0*32 + (l>>4)*8 + j]
__global__ void prep_w_frag(const float* __restrict__ w, __bf16* __restrict__ wf) {
    int idx = blockIdx.x * 256 + threadIdx.x;   // 589824 total
    int j   = idx & 7;
    int l   = (idx >> 3) & 63;
    int o16 = (idx >> 9) & 15;
    int c0  = (idx >> 13) & 7;
    int k   = idx >> 16;
    int o = o16 * 16 + (l & 15);
    int c = c0 * 32 + (l >> 4) * 8 + j;
    wf[idx] = (__bf16)w[(size_t)(o * 256 + c) * 9 + k];
}

// weight transpose for the 18-ch offset head: [18][256][3][3] -> [9][18][256] fp32
__global__ void transpose_w3(const float* __restrict__ w, float* __restrict__ wt, int Co) {
    int idx = blockIdx.x * 256 + threadIdx.x;
    int total = 9 * Co * 256;
    if (idx >= total) return;
    int c  = idx & 255;
    int o  = (idx >> 8) % Co;
    int kk = idx / (256 * Co);
    wt[idx] = w[(o * 256 + c) * 9 + kk];
}

// ---------------------------------------------------------------------------
// conv3x3 C256->C256 via bf16 MFMA. Block = one row y (64 px) x 256 o.
// Output t fp32 NHWC + GN stats.
__global__ __launch_bounds__(256, 2) void conv1_mfma(
    const __bf16* __restrict__ in_cl,   // [B,H,W,256] bf16
    const __bf16* __restrict__ wf,      // frag layout [9][8][16][64][8]
    const float* __restrict__ bias,     // [256]
    float* __restrict__ t_out,          // [B,H,W,256] fp32
    float* __restrict__ stats)          // + b*64
{
    __shared__ __bf16 Vt[66 * 264];
    __shared__ float groupStats[64];
    int y  = blockIdx.x;
    int bb = blockIdx.y;
    int t  = threadIdx.x;
    int w  = t >> 6;
    int l  = t & 63;
    int quad = l >> 4;
    int l15  = l & 15;
    if (t < 64) groupStats[t] = 0.f;

    const __bf16* inb = in_cl + (size_t)bb * HWW * CC;
    f32x4 acc[4][4];   // [pt][ot]
    #pragma unroll
    for (int i = 0; i < 4; ++i)
        #pragma unroll
        for (int j = 0; j < 4; ++j)
            acc[i][j] = (f32x4){0.f, 0.f, 0.f, 0.f};

    for (int ky = 0; ky < 3; ++ky) {
        int yy = y + ky - 1;
        bool yok = (yy >= 0 && yy < HH);
        __syncthreads();
        // stage row yy, x in [-1, 64], 256 c (bf16), zero OOB
        for (int u = t; u < 66 * 64; u += 256) {
            int xl = u >> 6, cu = u & 63;
            int gx = xl - 1;
            uint2 val = make_uint2(0u, 0u);
            if (yok && gx >= 0 && gx < WW)
                val = *(const uint2*)(inb + ((size_t)(yy * WW + gx)) * CC + cu * 4);
            *(uint2*)&Vt[xl * 264 + cu * 4] = val;
        }
        __syncthreads();
        #pragma unroll
        for (int kx = 0; kx < 3; ++kx) {
            int k = ky * 3 + kx;
            const bf16x8* wbase = (const bf16x8*)(wf + (size_t)k * 65536);
            for (int c0 = 0; c0 < 8; ++c0) {
                bf16x8 a[4], bfr[4];
                #pragma unroll
                for (int pt = 0; pt < 4; ++pt)
                    a[pt] = *(const bf16x8*)&Vt[(pt*16 + l15 + kx) * 264 + c0*32 + quad*8];
                #pragma unroll
                for (int ot = 0; ot < 4; ++ot)
                    bfr[ot] = wbase[(c0 * 16 + (w*4 + ot)) * 64 + l];
                #pragma unroll
                for (int pt = 0; pt < 4; ++pt)
                    #pragma unroll
                    for (int ot = 0; ot < 4; ++ot)
                        acc[pt][ot] = __builtin_amdgcn_mfma_f32_16x16x32_bf16(
                            a[pt], bfr[ot], acc[pt][ot], 0, 0, 0);
            }
        }
    }
    // epilogue: D[m=px][n=o]; px = pt*16 + quad*4 + r; o = w*64 + ot*16 + l15
    #pragma unroll
    for (int ot = 0; ot < 4; ++ot) {
        int o = w * 64 + ot * 16 + l15;
        float bi = bias[o];
        float s1 = 0.f, s2 = 0.f;
        #pragma unroll
        for (int pt = 0; pt < 4; ++pt)
            #pragma unroll
            for (int r = 0; r < 4; ++r) {
                float v = acc[pt][ot][r] + bi;
                int px = pt * 16 + quad * 4 + r;
                t_out[(((size_t)bb * HH + y) * WW + px) * CC + o] = v;
                s1 += v; s2 += v * v;
            }
        s1 += __shfl_xor(s1, 16, 64); s1 += __shfl_xor(s1, 32, 64);
        s2 += __shfl_xor(s2, 16, 64); s2 += __shfl_xor(s2, 32, 64);
        if (quad == 0) {
            atomicAdd(&groupStats[(o >> 3) * 2],     s1);
            atomicAdd(&groupStats[(o >> 3) * 2 + 1], s2);
        }
    }
    __syncthreads();
    if (t < 64) atomicAdd(&stats[bb * 64 + t], groupStats[t]);
}

// ---------------------------------------------------------------------------
// GN + ReLU on channels-last fp32 tensor, in place.
__global__ void gn_relu_cl(float* __restrict__ t, const float* __restrict__ stats,
                           const float* __restrict__ gamma, const float* __restrict__ beta) {
    size_t e = ((size_t)blockIdx.x * 256 + threadIdx.x) * 4;
    int c = (int)(e & 255);
    int b = (int)(e >> 20);
    int g = c >> 3;
    float mu = stats[(b*32 + g)*2] * (1.f / GN_CNT);
    float ms = stats[(b*32 + g)*2 + 1] * (1.f / GN_CNT);
    float rs = rsqrtf(ms - mu*mu + 1e-5f);
    float4 vv = *(const float4*)(t + e);
    float4 r;
    r.x = fmaxf((vv.x - mu)*rs*gamma[c]   + beta[c],   0.f);
    r.y = fmaxf((vv.y - mu)*rs*gamma[c+1] + beta[c+1], 0.f);
    r.z = fmaxf((vv.z - mu)*rs*gamma[c+2] + beta[c+2], 0.f);
    r.w = fmaxf((vv.w - mu)*rs*gamma[c+3] + beta[c+3], 0.f);
    *(float4*)(t + e) = r;
}

// ---------------------------------------------------------------------------
// conv3x3 C256->18 (offset head), fp32. Writes pts NCHW.
__global__ __launch_bounds__(256, 2) void conv3x3_c18(
    const float* __restrict__ in_cl,   // [B,H,W,256] fp32
    const float* __restrict__ wt,      // [9][18][256]
    const float* __restrict__ bias,    // [18]
    float* __restrict__ pts)           // [B,18,H,W]
{
    __shared__ float v[66 * 132];
    int y = blockIdx.x;
    int b = blockIdx.y;
    int x  = threadIdx.x & 63;
    int oq = threadIdx.x >> 6;
    int no = (oq < 2) ? 5 : 4;
    float acc[5] = {0.f, 0.f, 0.f, 0.f, 0.f};

    for (int ky = 0; ky < 3; ++ky) {
        int yy = y + ky - 1;
        bool yok = (yy >= 0 && yy < HH);
        const float* src = in_cl + ((size_t)(b*HH + (yok ? yy : 0)) * WW) * CC;
        for (int ch = 0; ch < 2; ++ch) {
            __syncthreads();
            int cs = threadIdx.x & 127;
            int xp = threadIdx.x >> 7;
            for (int xx = xp; xx < 66; xx += 2) {
                int gx = xx - 1;
                float val = 0.f;
                if (yok && gx >= 0 && gx < WW) val = src[(size_t)gx*CC + ch*128 + cs];
                v[xx * 132 + cs] = val;
            }
            __syncthreads();
            for (int kx = 0; kx < 3; ++kx) {
                int xi = x + kx;
                for (int c4 = 0; c4 < 32; ++c4) {
                    float4 vq = *(const float4*)(&v[xi * 132 + c4 * 4]);
                    #pragma unroll
                    for (int j = 0; j < 5; ++j) {
                        if (j < no) {
                            int o = oq + 4 * j;
                            float4 wq = *(const float4*)(&wt[((size_t)((ky*3+kx)*18 + o))*256 + ch*128 + c4*4]);
                            acc[j] += wq.x*vq.x + wq.y*vq.y + wq.z*vq.z + wq.w*vq.w;
                        }
                    }
                }
            }
        }
    }
    for (int j = 0; j < no; ++j) {
        int o = oq + 4 * j;
        pts[(((size_t)b*18 + o)*HH + y)*WW + x] = acc[j] + bias[o];
    }
}

// ---------------------------------------------------------------------------
// Deformable conv via bf16 MFMA. Block = one row y (64 px) x 256 o.
// grid (64 y, 4 b, 2 which).
__global__ __launch_bounds__(256, 2) void deform_mfma(
    const __bf16* __restrict__ cls_cl, const __bf16* __restrict__ reg_cl, // NHWC bf16
    const __bf16* __restrict__ wfc, const __bf16* __restrict__ wfr,       // frag layout
    const float* __restrict__ pts,                                        // [B,18,H,W]
    float* __restrict__ out_cls, float* __restrict__ out_reg,             // [B,256,H,W]
    float* __restrict__ stats)                                            // base of stats[]
{
    __shared__ float pairW4[576 * 4];
    __shared__ int   pairO4[576 * 4];
    __shared__ __bf16 Vt[64 * 264];
    __shared__ float groupStats[64];

    int y  = blockIdx.x;
    int bb = blockIdx.y;
    int which = blockIdx.z;
    const __bf16* featb = (which ? reg_cl : cls_cl) + (size_t)bb * HWW * CC;
    const __bf16* wf    = which ? wfr : wfc;
    float* outp   = which ? out_reg : out_cls;
    float* statsP = stats + 256 + which * 256 + bb * 64;

    int t = threadIdx.x;
    int w = t >> 6;
    int l = t & 63;
    int quad = l >> 4;
    int l15  = l & 15;

    if (t < 64) groupStats[t] = 0.f;
    // phase 0: per (px,k) bilinear weights + clamped corner offsets
    for (int j = t; j < 576; j += 256) {
        int k = j >> 6;
        int x = j & 63;
        float py  = pts[(((size_t)bb*18 + 2*k)*HH + y)*WW + x] + (float)y;
        float pxf = pts[(((size_t)bb*18 + 2*k + 1)*HH + y)*WW + x] + (float)x;
        float y0f = floorf(py), x0f = floorf(pxf);
        float wy = py - y0f, wx = pxf - x0f;
        int iy0 = (int)y0f, ix0 = (int)x0f;
        int iy1 = iy0 + 1,  ix1 = ix0 + 1;
        bool vy0 = (iy0 >= 0 && iy0 < HH), vy1 = (iy1 >= 0 && iy1 < HH);
        bool vx0 = (ix0 >= 0 && ix0 < WW), vx1 = (ix1 >= 0 && ix1 < WW);
        int cy0 = min(max(iy0, 0), HH-1), cy1 = min(max(iy1, 0), HH-1);
        int cx0 = min(max(ix0, 0), WW-1), cx1 = min(max(ix1, 0), WW-1);
        pairW4[j*4+0] = (1.f-wy)*(1.f-wx) * ((vy0 && vx0) ? 1.f : 0.f);
        pairW4[j*4+1] = (1.f-wy)*wx       * ((vy0 && vx1) ? 1.f : 0.f);
        pairW4[j*4+2] = wy*(1.f-wx)       * ((vy1 && vx0) ? 1.f : 0.f);
        pairW4[j*4+3] = wy*wx             * ((vy1 && vx1) ? 1.f : 0.f);
        pairO4[j*4+0] = (cy0*WW + cx0)*CC;
        pairO4[j*4+1] = (cy0*WW + cx1)*CC;
        pairO4[j*4+2] = (cy1*WW + cx0)*CC;
        pairO4[j*4+3] = (cy1*WW + cx1)*CC;
    }
    __syncthreads();

    f32x4 acc[4][4];   // [ot][pt]
    #pragma unroll
    for (int i = 0; i < 4; ++i)
        #pragma unroll
        for (int j = 0; j < 4; ++j)
            acc[i][j] = (f32x4){0.f, 0.f, 0.f, 0.f};

    for (int k = 0; k < KP; ++k) {
        // sampling: wave w handles px = w*16 .. w*16+15; lane l -> channels 4l..4l+3
        for (int i = 0; i < 16; ++i) {
            int px = w * 16 + i;
            int j  = k * 64 + px;
            float4 wv = *(const float4*)&pairW4[j * 4];
            int4   ov = *(const int4*)&pairO4[j * 4];
            uint2 q00 = *(const uint2*)(featb + ov.x + 4*l);
            uint2 q01 = *(const uint2*)(featb + ov.y + 4*l);
            uint2 q10 = *(const uint2*)(featb + ov.z + 4*l);
            uint2 q11 = *(const uint2*)(featb + ov.w + 4*l);
            float v0 = wv.x*bflo(q00.x) + wv.y*bflo(q01.x) + wv.z*bflo(q10.x) + wv.w*bflo(q11.x);
            float v1 = wv.x*bfhi(q00.x) + wv.y*bfhi(q01.x) + wv.z*bfhi(q10.x) + wv.w*bfhi(q11.x);
            float v2 = wv.x*bflo(q00.y) + wv.y*bflo(q01.y) + wv.z*bflo(q10.y) + wv.w*bflo(q11.y);
            float v3 = wv.x*bfhi(q00.y) + wv.y*bfhi(q01.y) + wv.z*bfhi(q10.y) + wv.w*bfhi(q11.y);
            __bf16 o4[4] = {(__bf16)v0, (__bf16)v1, (__bf16)v2, (__bf16)v3};
            *(uint2*)&Vt[px * 264 + 4*l] = *(const uint2*)o4;
        }
        __syncthreads();
        const bf16x8* wbase = (const bf16x8*)(wf + (size_t)k * 65536);
        for (int c0 = 0; c0 < 8; ++c0) {
            bf16x8 a[4], bfr[4];
            #pragma unroll
            for (int pt = 0; pt < 4; ++pt)
                a[pt] = *(const bf16x8*)&Vt[(pt*16 + l15) * 264 + c0*32 + quad*8];
            #pragma unroll
            for (int ot = 0; ot < 4; ++ot)
                bfr[ot] = wbase[(c0 * 16 + (w*4 + ot)) * 64 + l];
            #pragma unroll
            for (int ot = 0; ot < 4; ++ot)
                #pragma unroll
                for (int pt = 0; pt < 4; ++pt)
                    acc[ot][pt] = __builtin_amdgcn_mfma_f32_16x16x32_bf16(
                        bfr[ot], a[pt], acc[ot][pt], 0, 0, 0);
        }
        __syncthreads();
    }
    // epilogue: D[m=o][n=px]; o = w*64 + ot*16 + quad*4 + r; px = pt*16 + l15
    #pragma unroll
    for (int ot = 0; ot < 4; ++ot)
        #pragma unroll
        for (int r = 0; r < 4; ++r) {
            int o = w * 64 + ot * 16 + quad * 4 + r;
            float* orow = outp + ((size_t)(bb*CC + o))*HWW + y*WW + l15;
            float s1 = 0.f, s2 = 0.f;
            #pragma unroll
            for (int pt = 0; pt < 4; ++pt) {
                float v = acc[ot][pt][r];
                orow[pt * 16] = v;
                s1 += v; s2 += v * v;
            }
            s1 += __shfl_xor(s1, 1, 64); s1 += __shfl_xor(s1, 2, 64);
            s1 += __shfl_xor(s1, 4, 64); s1 += __shfl_xor(s1, 8, 64);
            s2 += __shfl_xor(s2, 1, 64); s2 += __shfl_xor(s2, 2, 64);
            s2 += __shfl_xor(s2, 4, 64); s2 += __shfl_xor(s2, 8, 64);
            if (l15 == 0) {
                atomicAdd(&groupStats[(o >> 3) * 2],     s1);
                atomicAdd(&groupStats[(o >> 3) * 2 + 1], s2);
            }
        }
    __syncthreads();
    if (t < 64) atomicAdd(&statsP[t], groupStats[t]);
}

// ---------------------------------------------------------------------------
// GN + ReLU on NCHW deform outputs -> final outputs.
__global__ void gn_relu_nchw(const float* __restrict__ in_cls, const float* __restrict__ in_reg,
                             float* __restrict__ out_cls, float* __restrict__ out_reg,
                             const float* __restrict__ stats_base,
                             const float* __restrict__ gcls, const float* __restrict__ bcls,
                             const float* __restrict__ greg, const float* __restrict__ breg) {
    int which = blockIdx.y;
    const float* in  = which ? in_reg  : in_cls;
    float* out       = which ? out_reg : out_cls;
    const float* st  = stats_base + (which ? 512 : 256);
    const float* gg  = which ? greg : gcls;
    const float* be  = which ? breg : bcls;
    size_t e = ((size_t)blockIdx.x * 256 + threadIdx.x) * 4;
    int c = (int)((e >> 12) & 255);
    int b = (int)(e >> 20);
    int g = c >> 3;
    float mu = st[(b*32 + g)*2] * (1.f / GN_CNT);
    float ms = st[(b*32 + g)*2 + 1] * (1.f / GN_CNT);
    float rs = rsqrtf(ms - mu*mu + 1e-5f);
    float ga = gg[c], bb = be[c];
    float4 vv = *(const float4*)(in + e);
    float4 r;
    r.x = fmaxf((vv.x - mu)*rs*ga + bb, 0.f);
    r.y = fmaxf((vv.y - mu)*rs*ga + bb, 0.f);
    r.z = fmaxf((vv.z - mu)*rs*ga + bb, 0.f);
    r.w = fmaxf((vv.w - mu)*rs*ga + bb, 0.f);
    *(float4*)(out + e) = r;
}

// ---------------------------------------------------------------------------
extern "C" void kernel_launch(void* const* d_in, const int* in_sizes, int n_in,
                              void* d_out, int out_size, void* d_ws, size_t ws_size,
                              hipStream_t stream) {
    (void)in_sizes; (void)n_in; (void)out_size; (void)ws_size;
    const float* cls_feat = (const float*)d_in[0];
    const float* reg_feat = (const float*)d_in[1];
    const float* offc_w   = (const float*)d_in[2];
    const float* offc_b   = (const float*)d_in[3];
    const float* offc_g   = (const float*)d_in[4];
    const float* offc_bt  = (const float*)d_in[5];
    const float* offo_w   = (const float*)d_in[6];
    const float* offo_b   = (const float*)d_in[7];
    const float* clsdc_w  = (const float*)d_in[8];
    const float* cls_g    = (const float*)d_in[9];
    const float* cls_bt   = (const float*)d_in[10];
    const float* regdc_w  = (const float*)d_in[11];
    const float* reg_g    = (const float*)d_in[12];
    const float* reg_bt   = (const float*)d_in[13];
    float* out = (float*)d_out;

    char* ws = (char*)d_ws;
    __bf16* reg_cl = (__bf16*)ws;                       // 8 MB
    __bf16* cls_cl = (__bf16*)(ws + 8388608);           // 8 MB
    float*  t_cl   = (float*)(ws + 16777216);           // 16 MB
    float*  dc_reg = (float*)(ws + 33554432);           // 16 MB
    __bf16* wt1f   = (__bf16*)(ws + 50331648);          // 1.15 MB
    __bf16* wtcf   = (__bf16*)(ws + 51511296);
    __bf16* wtrf   = (__bf16*)(ws + 52690944);
    float*  wt2    = (float*)(ws + 53870592);           // 162 KB
    float*  stats  = (float*)(ws + 54036480);           // 768 floats

    float* pts     = out;                 // [4,18,64,64]
    float* out_cls = out + 294912;
    float* out_reg = out + 294912 + FEL;
    float* dc_cls  = t_cl;                // alias: t consumed before deform runs

    hipLaunchKernelGGL(zero_stats, dim3(3), dim3(256), 0, stream, stats);
    hipLaunchKernelGGL(transpose_feat, dim3(4, 64, 8), dim3(256), 0, stream,
                       cls_feat, reg_feat, cls_cl, reg_cl);
    hipLaunchKernelGGL(prep_w_frag, dim3(2304), dim3(256), 0, stream, offc_w, wt1f);
    hipLaunchKernelGGL(prep_w_frag, dim3(2304), dim3(256), 0, stream, clsdc_w, wtcf);
    hipLaunchKernelGGL(prep_w_frag, dim3(2304), dim3(256), 0, stream, regdc_w, wtrf);
    hipLaunchKernelGGL(transpose_w3, dim3(162), dim3(256), 0, stream, offo_w, wt2, 18);
    hipLaunchKernelGGL(conv1_mfma, dim3(64, 4), dim3(256), 0, stream,
                       reg_cl, wt1f, offc_b, t_cl, stats);
    hipLaunchKernelGGL(gn_relu_cl, dim3(4096), dim3(256), 0, stream,
                       t_cl, stats, offc_g, offc_bt);
    hipLaunchKernelGGL(conv3x3_c18, dim3(64, 4), dim3(256), 0, stream,
                       t_cl, wt2, offo_b, pts);
    hipLaunchKernelGGL(deform_mfma, dim3(64, 4, 2), dim3(256), 0, stream,
                       cls_cl, reg_cl, wtcf, wtrf, pts, dc_cls, dc_reg, stats);
    hipLaunchKernelGGL(gn_relu_nchw, dim3(4096, 2), dim3(256), 0, stream,
                       dc_cls, dc_reg, out_cls, out_reg,
                       stats, cls_g, cls_bt, reg_g, reg_bt);
}

// Round 3
// 313.310 us; speedup vs baseline: 5.7343x; 1.6111x over previous
//
#include <hip/hip_runtime.h>
#include <math.h>

#define BB 4
#define CC 256
#define HH 64
#define WW 64
#define KP 9
#define GG 32
#define HWW (HH*WW)                 // 4096
#define FEL ((size_t)BB*CC*HH*WW)   // 4194304
#define GN_CNT 32768.0f             // (CC/GG)*H*W

typedef __bf16 bf16x8 __attribute__((ext_vector_type(8)));
typedef float  f32x4  __attribute__((ext_vector_type(4)));

__device__ __forceinline__ float bflo(unsigned u) {
    union { unsigned u; float f; } x; x.u = u << 16; return x.f;
}
__device__ __forceinline__ float bfhi(unsigned u) {
    union { unsigned u; float f; } x; x.u = u & 0xffff0000u; return x.f;
}

// ---------------------------------------------------------------------------
__global__ void zero_stats(float* s) {
    int i = blockIdx.x * 256 + threadIdx.x;
    if (i < 768) s[i] = 0.f;
}

// ---------------------------------------------------------------------------
// NCHW fp32 -> NHWC bf16 for both feature maps.
__global__ void transpose_feat(const float* __restrict__ cls,
                               const float* __restrict__ reg,
                               __bf16* __restrict__ out_cls,
                               __bf16* __restrict__ out_reg) {
    __shared__ float tile[64][65];
    int c0 = blockIdx.x * 64;
    int y  = blockIdx.y;
    int b  = blockIdx.z & 3;
    const float* in = (blockIdx.z >> 2) ? reg : cls;
    __bf16* out     = (blockIdx.z >> 2) ? out_reg : out_cls;
    int lx = threadIdx.x & 63;
    int q  = threadIdx.x >> 6;
    for (int j = 0; j < 16; ++j) {
        int ci = q * 16 + j;
        tile[ci][lx] = in[(((size_t)b*CC + c0 + ci)*HH + y)*WW + lx];
    }
    __syncthreads();
    for (int j = 0; j < 16; ++j) {
        int xi = q * 16 + j;
        out[(((size_t)b*HH + y)*WW + xi)*CC + c0 + lx] = (__bf16)tile[lx][xi];
    }
}

// ---------------------------------------------------------------------------
// fp32 [O=256][C=256][9] -> bf16 B-fragment order [9][c0:8][o16:16][lane:64][j:8]
// lane l holds W[o16*16 + (l&15)][c0*32 + (l>>4)*8 + j]
__global__ void prep_w_frag(const float* __restrict__ w, __bf16* __restrict__ wf) {
    int idx = blockIdx.x * 256 + threadIdx.x;   // 589824 total
    int j   = idx & 7;
    int l   = (idx >> 3) & 63;
    int o16 = (idx >> 9) & 15;
    int c0  = (idx >> 13) & 7;
    int k   = idx >> 16;
    int o = o16 * 16 + (l & 15);
    int c = c0 * 32 + (l >> 4) * 8 + j;
    wf[idx] = (__bf16)w[(size_t)(o * 256 + c) * 9 + k];
}

// fp32 [O=18][C=256][9] -> bf16 frag [9][c0:8][o16:2][lane:64][j:8], zero-pad o>=18
__global__ void prep_w18_frag(const float* __restrict__ w, __bf16* __restrict__ wf) {
    int idx = blockIdx.x * 256 + threadIdx.x;   // 73728 total
    int j   = idx & 7;
    int l   = (idx >> 3) & 63;
    int o16 = (idx >> 9) & 1;
    int c0  = (idx >> 10) & 7;
    int k   = idx >> 13;
    int o = o16 * 16 + (l & 15);
    int c = c0 * 32 + (l >> 4) * 8 + j;
    float v = (o < 18) ? w[(size_t)(o * 256 + c) * 9 + k] : 0.f;
    wf[idx] = (__bf16)v;
}

// ---------------------------------------------------------------------------
// conv3x3 C256->C256 via bf16 MFMA. Block = one row y (64 px) x 256 o.
// Output t bf16 NHWC + GN stats (fp32, from registers).
__global__ __launch_bounds__(256, 2) void conv1_mfma(
    const __bf16* __restrict__ in_cl,   // [B,H,W,256] bf16
    const __bf16* __restrict__ wf,      // frag layout [9][8][16][64][8]
    const float* __restrict__ bias,     // [256]
    __bf16* __restrict__ t_out,         // [B,H,W,256] bf16
    float* __restrict__ stats)          // + b*64
{
    __shared__ __bf16 Vt[66 * 264];
    __shared__ float groupStats[64];
    int y  = blockIdx.x;
    int bb = blockIdx.y;
    int t  = threadIdx.x;
    int w  = t >> 6;
    int l  = t & 63;
    int quad = l >> 4;
    int l15  = l & 15;
    if (t < 64) groupStats[t] = 0.f;

    const __bf16* inb = in_cl + (size_t)bb * HWW * CC;
    f32x4 acc[4][4];   // [pt][ot]
    #pragma unroll
    for (int i = 0; i < 4; ++i)
        #pragma unroll
        for (int j = 0; j < 4; ++j)
            acc[i][j] = (f32x4){0.f, 0.f, 0.f, 0.f};

    for (int ky = 0; ky < 3; ++ky) {
        int yy = y + ky - 1;
        bool yok = (yy >= 0 && yy < HH);
        __syncthreads();
        for (int u = t; u < 66 * 64; u += 256) {
            int xl = u >> 6, cu = u & 63;
            int gx = xl - 1;
            uint2 val = make_uint2(0u, 0u);
            if (yok && gx >= 0 && gx < WW)
                val = *(const uint2*)(inb + ((size_t)(yy * WW + gx)) * CC + cu * 4);
            *(uint2*)&Vt[xl * 264 + cu * 4] = val;
        }
        __syncthreads();
        #pragma unroll
        for (int kx = 0; kx < 3; ++kx) {
            int k = ky * 3 + kx;
            const bf16x8* wbase = (const bf16x8*)(wf + (size_t)k * 65536);
            for (int c0 = 0; c0 < 8; ++c0) {
                bf16x8 a[4], bfr[4];
                #pragma unroll
                for (int pt = 0; pt < 4; ++pt)
                    a[pt] = *(const bf16x8*)&Vt[(pt*16 + l15 + kx) * 264 + c0*32 + quad*8];
                #pragma unroll
                for (int ot = 0; ot < 4; ++ot)
                    bfr[ot] = wbase[(c0 * 16 + (w*4 + ot)) * 64 + l];
                #pragma unroll
                for (int pt = 0; pt < 4; ++pt)
                    #pragma unroll
                    for (int ot = 0; ot < 4; ++ot)
                        acc[pt][ot] = __builtin_amdgcn_mfma_f32_16x16x32_bf16(
                            a[pt], bfr[ot], acc[pt][ot], 0, 0, 0);
            }
        }
    }
    // epilogue: D[m=px][n=o]; px = pt*16 + quad*4 + r; o = w*64 + ot*16 + l15
    #pragma unroll
    for (int ot = 0; ot < 4; ++ot) {
        int o = w * 64 + ot * 16 + l15;
        float bi = bias[o];
        float s1 = 0.f, s2 = 0.f;
        #pragma unroll
        for (int pt = 0; pt < 4; ++pt)
            #pragma unroll
            for (int r = 0; r < 4; ++r) {
                float v = acc[pt][ot][r] + bi;
                int px = pt * 16 + quad * 4 + r;
                t_out[(((size_t)bb * HH + y) * WW + px) * CC + o] = (__bf16)v;
                s1 += v; s2 += v * v;
            }
        s1 += __shfl_xor(s1, 16, 64); s1 += __shfl_xor(s1, 32, 64);
        s2 += __shfl_xor(s2, 16, 64); s2 += __shfl_xor(s2, 32, 64);
        if (quad == 0) {
            atomicAdd(&groupStats[(o >> 3) * 2],     s1);
            atomicAdd(&groupStats[(o >> 3) * 2 + 1], s2);
        }
    }
    __syncthreads();
    if (t < 64) atomicAdd(&stats[bb * 64 + t], groupStats[t]);
}

// ---------------------------------------------------------------------------
// GN + ReLU on channels-last bf16 tensor, in place. 8 bf16 per thread.
__global__ void gn_relu_bf(__bf16* __restrict__ t, const float* __restrict__ stats,
                           const float* __restrict__ gamma, const float* __restrict__ beta) {
    size_t e = ((size_t)blockIdx.x * 256 + threadIdx.x) * 8;
    int c = (int)(e & 255);
    int b = (int)(e >> 20);
    int g = c >> 3;
    float mu = stats[(b*32 + g)*2] * (1.f / GN_CNT);
    float ms = stats[(b*32 + g)*2 + 1] * (1.f / GN_CNT);
    float rs = rsqrtf(ms - mu*mu + 1e-5f);
    uint4 q = *(const uint4*)(t + e);
    float v[8] = {bflo(q.x), bfhi(q.x), bflo(q.y), bfhi(q.y),
                  bflo(q.z), bfhi(q.z), bflo(q.w), bfhi(q.w)};
    __bf16 r[8];
    #pragma unroll
    for (int i = 0; i < 8; ++i)
        r[i] = (__bf16)fmaxf((v[i] - mu)*rs*gamma[c+i] + beta[c+i], 0.f);
    *(uint4*)(t + e) = *(const uint4*)r;
}

// ---------------------------------------------------------------------------
// Offset head conv3x3 C256->18 via bf16 MFMA (N padded to 32). Writes pts NCHW fp32.
__global__ __launch_bounds__(256, 2) void conv18_mfma(
    const __bf16* __restrict__ t_bf,    // [B,H,W,256] bf16 (post GN+ReLU)
    const __bf16* __restrict__ wf18,    // frag layout [9][8][2][64][8]
    const float* __restrict__ bias,     // [18]
    float* __restrict__ pts)            // [B,18,H,W]
{
    __shared__ __bf16 Vt[66 * 264];
    int y  = blockIdx.x;
    int bb = blockIdx.y;
    int t  = threadIdx.x;
    int w  = t >> 6;
    int l  = t & 63;
    int quad = l >> 4;
    int l15  = l & 15;
    const __bf16* inb = t_bf + (size_t)bb * HWW * CC;

    f32x4 acc[2];
    acc[0] = (f32x4){0.f, 0.f, 0.f, 0.f};
    acc[1] = (f32x4){0.f, 0.f, 0.f, 0.f};

    for (int ky = 0; ky < 3; ++ky) {
        int yy = y + ky - 1;
        bool yok = (yy >= 0 && yy < HH);
        __syncthreads();
        for (int u = t; u < 66 * 64; u += 256) {
            int xl = u >> 6, cu = u & 63;
            int gx = xl - 1;
            uint2 val = make_uint2(0u, 0u);
            if (yok && gx >= 0 && gx < WW)
                val = *(const uint2*)(inb + ((size_t)(yy * WW + gx)) * CC + cu * 4);
            *(uint2*)&Vt[xl * 264 + cu * 4] = val;
        }
        __syncthreads();
        #pragma unroll
        for (int kx = 0; kx < 3; ++kx) {
            int k = ky * 3 + kx;
            const bf16x8* wbase = (const bf16x8*)(wf18 + (size_t)k * 8192);
            for (int c0 = 0; c0 < 8; ++c0) {
                bf16x8 a = *(const bf16x8*)&Vt[(w*16 + l15 + kx) * 264 + c0*32 + quad*8];
                #pragma unroll
                for (int o16 = 0; o16 < 2; ++o16) {
                    bf16x8 bfr = wbase[(c0 * 2 + o16) * 64 + l];
                    acc[o16] = __builtin_amdgcn_mfma_f32_16x16x32_bf16(a, bfr, acc[o16], 0, 0, 0);
                }
            }
        }
    }
    // D[m=px_local][n=o]: px = w*16 + quad*4 + r, o = o16*16 + l15
    #pragma unroll
    for (int o16 = 0; o16 < 2; ++o16) {
        int o = o16 * 16 + l15;
        if (o < 18) {
            float bi = bias[o];
            float4 st;
            st.x = acc[o16][0] + bi;
            st.y = acc[o16][1] + bi;
            st.z = acc[o16][2] + bi;
            st.w = acc[o16][3] + bi;
            *(float4*)(pts + (((size_t)bb*18 + o)*HH + y)*WW + w*16 + quad*4) = st;
        }
    }
}

// ---------------------------------------------------------------------------
// Deformable conv via bf16 MFMA. Block = one row y (64 px) x 256 o.
// grid (64 y, 4 b, 2 which). Output bf16 NCHW + GN stats.
__global__ __launch_bounds__(256, 2) void deform_mfma(
    const __bf16* __restrict__ cls_cl, const __bf16* __restrict__ reg_cl, // NHWC bf16
    const __bf16* __restrict__ wfc, const __bf16* __restrict__ wfr,       // frag layout
    const float* __restrict__ pts,                                        // [B,18,H,W]
    __bf16* __restrict__ out_cls, __bf16* __restrict__ out_reg,           // [B,256,H,W] bf16
    float* __restrict__ stats)                                            // base of stats[]
{
    __shared__ float pairW4[576 * 4];
    __shared__ int   pairO4[576 * 4];
    __shared__ __bf16 Vt[64 * 264];
    __shared__ float groupStats[64];

    int y  = blockIdx.x;
    int bb = blockIdx.y;
    int which = blockIdx.z;
    const __bf16* featb = (which ? reg_cl : cls_cl) + (size_t)bb * HWW * CC;
    const __bf16* wf    = which ? wfr : wfc;
    __bf16* outp  = which ? out_reg : out_cls;
    float* statsP = stats + 256 + which * 256 + bb * 64;

    int t = threadIdx.x;
    int w = t >> 6;
    int l = t & 63;
    int quad = l >> 4;
    int l15  = l & 15;

    if (t < 64) groupStats[t] = 0.f;
    for (int j = t; j < 576; j += 256) {
        int k = j >> 6;
        int x = j & 63;
        float py  = pts[(((size_t)bb*18 + 2*k)*HH + y)*WW + x] + (float)y;
        float pxf = pts[(((size_t)bb*18 + 2*k + 1)*HH + y)*WW + x] + (float)x;
        float y0f = floorf(py), x0f = floorf(pxf);
        float wy = py - y0f, wx = pxf - x0f;
        int iy0 = (int)y0f, ix0 = (int)x0f;
        int iy1 = iy0 + 1,  ix1 = ix0 + 1;
        bool vy0 = (iy0 >= 0 && iy0 < HH), vy1 = (iy1 >= 0 && iy1 < HH);
        bool vx0 = (ix0 >= 0 && ix0 < WW), vx1 = (ix1 >= 0 && ix1 < WW);
        int cy0 = min(max(iy0, 0), HH-1), cy1 = min(max(iy1, 0), HH-1);
        int cx0 = min(max(ix0, 0), WW-1), cx1 = min(max(ix1, 0), WW-1);
        pairW4[j*4+0] = (1.f-wy)*(1.f-wx) * ((vy0 && vx0) ? 1.f : 0.f);
        pairW4[j*4+1] = (1.f-wy)*wx       * ((vy0 && vx1) ? 1.f : 0.f);
        pairW4[j*4+2] = wy*(1.f-wx)       * ((vy1 && vx0) ? 1.f : 0.f);
        pairW4[j*4+3] = wy*wx             * ((vy1 && vx1) ? 1.f : 0.f);
        pairO4[j*4+0] = (cy0*WW + cx0)*CC;
        pairO4[j*4+1] = (cy0*WW + cx1)*CC;
        pairO4[j*4+2] = (cy1*WW + cx0)*CC;
        pairO4[j*4+3] = (cy1*WW + cx1)*CC;
    }
    __syncthreads();

    f32x4 acc[4][4];   // [ot][pt]
    #pragma unroll
    for (int i = 0; i < 4; ++i)
        #pragma unroll
        for (int j = 0; j < 4; ++j)
            acc[i][j] = (f32x4){0.f, 0.f, 0.f, 0.f};

    for (int k = 0; k < KP; ++k) {
        for (int i = 0; i < 16; ++i) {
            int px = w * 16 + i;
            int j  = k * 64 + px;
            float4 wv = *(const float4*)&pairW4[j * 4];
            int4   ov = *(const int4*)&pairO4[j * 4];
            uint2 q00 = *(const uint2*)(featb + ov.x + 4*l);
            uint2 q01 = *(const uint2*)(featb + ov.y + 4*l);
            uint2 q10 = *(const uint2*)(featb + ov.z + 4*l);
            uint2 q11 = *(const uint2*)(featb + ov.w + 4*l);
            float v0 = wv.x*bflo(q00.x) + wv.y*bflo(q01.x) + wv.z*bflo(q10.x) + wv.w*bflo(q11.x);
            float v1 = wv.x*bfhi(q00.x) + wv.y*bfhi(q01.x) + wv.z*bfhi(q10.x) + wv.w*bfhi(q11.x);
            float v2 = wv.x*bflo(q00.y) + wv.y*bflo(q01.y) + wv.z*bflo(q10.y) + wv.w*bflo(q11.y);
            float v3 = wv.x*bfhi(q00.y) + wv.y*bfhi(q01.y) + wv.z*bfhi(q10.y) + wv.w*bfhi(q11.y);
            __bf16 o4[4] = {(__bf16)v0, (__bf16)v1, (__bf16)v2, (__bf16)v3};
            *(uint2*)&Vt[px * 264 + 4*l] = *(const uint2*)o4;
        }
        __syncthreads();
        const bf16x8* wbase = (const bf16x8*)(wf + (size_t)k * 65536);
        for (int c0 = 0; c0 < 8; ++c0) {
            bf16x8 a[4], bfr[4];
            #pragma unroll
            for (int pt = 0; pt < 4; ++pt)
                a[pt] = *(const bf16x8*)&Vt[(pt*16 + l15) * 264 + c0*32 + quad*8];
            #pragma unroll
            for (int ot = 0; ot < 4; ++ot)
                bfr[ot] = wbase[(c0 * 16 + (w*4 + ot)) * 64 + l];
            #pragma unroll
            for (int ot = 0; ot < 4; ++ot)
                #pragma unroll
                for (int pt = 0; pt < 4; ++pt)
                    acc[ot][pt] = __builtin_amdgcn_mfma_f32_16x16x32_bf16(
                        bfr[ot], a[pt], acc[ot][pt], 0, 0, 0);
        }
        __syncthreads();
    }
    // epilogue: D[m=o][n=px]; o = w*64 + ot*16 + quad*4 + r; px = pt*16 + l15
    #pragma unroll
    for (int ot = 0; ot < 4; ++ot)
        #pragma unroll
        for (int r = 0; r < 4; ++r) {
            int o = w * 64 + ot * 16 + quad * 4 + r;
            __bf16* orow = outp + ((size_t)(bb*CC + o))*HWW + y*WW + l15;
            float s1 = 0.f, s2 = 0.f;
            #pragma unroll
            for (int pt = 0; pt < 4; ++pt) {
                float v = acc[ot][pt][r];
                orow[pt * 16] = (__bf16)v;
                s1 += v; s2 += v * v;
            }
            s1 += __shfl_xor(s1, 1, 64); s1 += __shfl_xor(s1, 2, 64);
            s1 += __shfl_xor(s1, 4, 64); s1 += __shfl_xor(s1, 8, 64);
            s2 += __shfl_xor(s2, 1, 64); s2 += __shfl_xor(s2, 2, 64);
            s2 += __shfl_xor(s2, 4, 64); s2 += __shfl_xor(s2, 8, 64);
            if (l15 == 0) {
                atomicAdd(&groupStats[(o >> 3) * 2],     s1);
                atomicAdd(&groupStats[(o >> 3) * 2 + 1], s2);
            }
        }
    __syncthreads();
    if (t < 64) atomicAdd(&statsP[t], groupStats[t]);
}

// ---------------------------------------------------------------------------
// GN + ReLU on bf16 NCHW deform outputs -> fp32 final outputs. 8 elems/thread.
__global__ void gn_relu_nchw(const __bf16* __restrict__ in_cls, const __bf16* __restrict__ in_reg,
                             float* __restrict__ out_cls, float* __restrict__ out_reg,
                             const float* __restrict__ stats_base,
                             const float* __restrict__ gcls, const float* __restrict__ bcls,
                             const float* __restrict__ greg, const float* __restrict__ breg) {
    int which = blockIdx.y;
    const __bf16* in = which ? in_reg  : in_cls;
    float* out       = which ? out_reg : out_cls;
    const float* st  = stats_base + (which ? 512 : 256);
    const float* gg  = which ? greg : gcls;
    const float* be  = which ? breg : bcls;
    size_t e = ((size_t)blockIdx.x * 256 + threadIdx.x) * 8;
    int c = (int)((e >> 12) & 255);
    int b = (int)(e >> 20);
    int g = c >> 3;
    float mu = st[(b*32 + g)*2] * (1.f / GN_CNT);
    float ms = st[(b*32 + g)*2 + 1] * (1.f / GN_CNT);
    float rs = rsqrtf(ms - mu*mu + 1e-5f);
    float ga = gg[c], bb = be[c];
    uint4 q = *(const uint4*)(in + e);
    float v[8] = {bflo(q.x), bfhi(q.x), bflo(q.y), bfhi(q.y),
                  bflo(q.z), bfhi(q.z), bflo(q.w), bfhi(q.w)};
    float4 r0, r1;
    r0.x = fmaxf((v[0] - mu)*rs*ga + bb, 0.f);
    r0.y = fmaxf((v[1] - mu)*rs*ga + bb, 0.f);
    r0.z = fmaxf((v[2] - mu)*rs*ga + bb, 0.f);
    r0.w = fmaxf((v[3] - mu)*rs*ga + bb, 0.f);
    r1.x = fmaxf((v[4] - mu)*rs*ga + bb, 0.f);
    r1.y = fmaxf((v[5] - mu)*rs*ga + bb, 0.f);
    r1.z = fmaxf((v[6] - mu)*rs*ga + bb, 0.f);
    r1.w = fmaxf((v[7] - mu)*rs*ga + bb, 0.f);
    *(float4*)(out + e)     = r0;
    *(float4*)(out + e + 4) = r1;
}

// ---------------------------------------------------------------------------
extern "C" void kernel_launch(void* const* d_in, const int* in_sizes, int n_in,
                              void* d_out, int out_size, void* d_ws, size_t ws_size,
                              hipStream_t stream) {
    (void)in_sizes; (void)n_in; (void)out_size; (void)ws_size;
    const float* cls_feat = (const float*)d_in[0];
    const float* reg_feat = (const float*)d_in[1];
    const float* offc_w   = (const float*)d_in[2];
    const float* offc_b   = (const float*)d_in[3];
    const float* offc_g   = (const float*)d_in[4];
    const float* offc_bt  = (const float*)d_in[5];
    const float* offo_w   = (const float*)d_in[6];
    const float* offo_b   = (const float*)d_in[7];
    const float* clsdc_w  = (const float*)d_in[8];
    const float* cls_g    = (const float*)d_in[9];
    const float* cls_bt   = (const float*)d_in[10];
    const float* regdc_w  = (const float*)d_in[11];
    const float* reg_g    = (const float*)d_in[12];
    const float* reg_bt   = (const float*)d_in[13];
    float* out = (float*)d_out;

    char* ws = (char*)d_ws;
    __bf16* reg_cl = (__bf16*)ws;                        // 8 MB
    __bf16* cls_cl = (__bf16*)(ws + 8388608);            // 8 MB
    __bf16* t_bf   = (__bf16*)(ws + 16777216);           // 8 MB
    __bf16* dc_cls = (__bf16*)(ws + 25165824);           // 8 MB
    __bf16* dc_reg = (__bf16*)(ws + 33554432);           // 8 MB
    __bf16* wt1f   = (__bf16*)(ws + 41943040);           // 1.18 MB
    __bf16* wtcf   = (__bf16*)(ws + 41943040 + 1179648);
    __bf16* wtrf   = (__bf16*)(ws + 41943040 + 2359296);
    __bf16* wf18   = (__bf16*)(ws + 41943040 + 3538944); // 147 KB
    float*  stats  = (float*)(ws + 41943040 + 3686400);  // 768 floats

    float* pts     = out;                 // [4,18,64,64]
    float* out_cls = out + 294912;
    float* out_reg = out + 294912 + FEL;

    hipLaunchKernelGGL(zero_stats, dim3(3), dim3(256), 0, stream, stats);
    hipLaunchKernelGGL(transpose_feat, dim3(4, 64, 8), dim3(256), 0, stream,
                       cls_feat, reg_feat, cls_cl, reg_cl);
    hipLaunchKernelGGL(prep_w_frag, dim3(2304), dim3(256), 0, stream, offc_w, wt1f);
    hipLaunchKernelGGL(prep_w_frag, dim3(2304), dim3(256), 0, stream, clsdc_w, wtcf);
    hipLaunchKernelGGL(prep_w_frag, dim3(2304), dim3(256), 0, stream, regdc_w, wtrf);
    hipLaunchKernelGGL(prep_w18_frag, dim3(288), dim3(256), 0, stream, offo_w, wf18);
    hipLaunchKernelGGL(conv1_mfma, dim3(64, 4), dim3(256), 0, stream,
                       reg_cl, wt1f, offc_b, t_bf, stats);
    hipLaunchKernelGGL(gn_relu_bf, dim3(4096), dim3(256), 0, stream,
                       t_bf, stats, offc_g, offc_bt);
    hipLaunchKernelGGL(conv18_mfma, dim3(64, 4), dim3(256), 0, stream,
                       t_bf, wf18, offo_b, pts);
    hipLaunchKernelGGL(deform_mfma, dim3(64, 4, 2), dim3(256), 0, stream,
                       cls_cl, reg_cl, wtcf, wtrf, pts, dc_cls, dc_reg, stats);
    hipLaunchKernelGGL(gn_relu_nchw, dim3(2048, 2), dim3(256), 0, stream,
                       dc_cls, dc_reg, out_cls, out_reg,
                       stats, cls_g, cls_bt, reg_g, reg_bt);
}